// Round 4
// baseline (411.544 us; speedup 1.0000x reference)
//
#include <hip/hip_runtime.h>
#include <math.h>

#define EPS 1e-5f

constexpr int B = 8, S = 1024, E = 512, H = 8;
constexpr int M = B * S;          // 8192 rows

typedef __attribute__((ext_vector_type(8))) short short8;  // 8 bf16 (4 VGPRs)
typedef __attribute__((ext_vector_type(4))) float f32x4;

// fp32 -> bf16 bits, round-to-nearest-even
static __device__ __forceinline__ unsigned short f2bf(float f) {
    unsigned int x = __float_as_uint(f);
    x += 0x7FFFu + ((x >> 16) & 1u);
    return (unsigned short)(x >> 16);
}
static __device__ __forceinline__ float bf2f(unsigned short u) {
    return __uint_as_float(((unsigned int)u) << 16);
}

// async global->LDS, 16B per lane (global_load_lds_dwordx4)
typedef __attribute__((address_space(3))) unsigned int  lds_uint;
typedef __attribute__((address_space(1))) unsigned int  glb_uint;
static __device__ __forceinline__ void gload16(const unsigned short* g, unsigned short* l) {
    __builtin_amdgcn_global_load_lds((const glb_uint*)g, (lds_uint*)l, 16, 0, 0);
}

// ---------------------------------------------------------------------------
// LN -> bf16: one wave per row (E=512, 8 elems/lane), stats via 64-lane shuffles.
// ---------------------------------------------------------------------------
__global__ __launch_bounds__(256) void ln_bf16_kernel(
    const float* __restrict__ x, const float* __restrict__ w,
    const float* __restrict__ bb, unsigned short* __restrict__ out) {
    int row = blockIdx.x * 4 + (threadIdx.x >> 6);
    int lane = threadIdx.x & 63;
    const float* xr = x + (size_t)row * E + lane * 8;
    float4 v0 = *(const float4*)xr;
    float4 v1 = *(const float4*)(xr + 4);
    float vv[8] = {v0.x, v0.y, v0.z, v0.w, v1.x, v1.y, v1.z, v1.w};
    float s = 0.f;
    #pragma unroll
    for (int i = 0; i < 8; i++) s += vv[i];
    #pragma unroll
    for (int o = 1; o < 64; o <<= 1) s += __shfl_xor(s, o);
    float mu = s * (1.0f / E);
    float qs = 0.f;
    #pragma unroll
    for (int i = 0; i < 8; i++) { float d = vv[i] - mu; qs += d * d; }
    #pragma unroll
    for (int o = 1; o < 64; o <<= 1) qs += __shfl_xor(qs, o);
    float rs = rsqrtf(qs * (1.0f / E) + EPS);
    float4 w0 = *(const float4*)(w + lane * 8), w1 = *(const float4*)(w + lane * 8 + 4);
    float4 b0 = *(const float4*)(bb + lane * 8), b1 = *(const float4*)(bb + lane * 8 + 4);
    float ww[8] = {w0.x, w0.y, w0.z, w0.w, w1.x, w1.y, w1.z, w1.w};
    float bv[8] = {b0.x, b0.y, b0.z, b0.w, b1.x, b1.y, b1.z, b1.w};
    short8 o8;
    #pragma unroll
    for (int i = 0; i < 8; i++) o8[i] = (short)f2bf((vv[i] - mu) * rs * ww[i] + bv[i]);
    *(short8*)(out + (size_t)row * E + lane * 8) = o8;
}

// ---------------------------------------------------------------------------
// Full LN (fp32 out) for the final output — wave-per-row.
// ---------------------------------------------------------------------------
__global__ __launch_bounds__(256) void ln_full_kernel(
    const float* __restrict__ x, const float* __restrict__ w,
    const float* __restrict__ bb, float* __restrict__ out) {
    int row = blockIdx.x * 4 + (threadIdx.x >> 6);
    int lane = threadIdx.x & 63;
    const float* xr = x + (size_t)row * E + lane * 8;
    float4 v0 = *(const float4*)xr;
    float4 v1 = *(const float4*)(xr + 4);
    float vv[8] = {v0.x, v0.y, v0.z, v0.w, v1.x, v1.y, v1.z, v1.w};
    float s = 0.f;
    #pragma unroll
    for (int i = 0; i < 8; i++) s += vv[i];
    #pragma unroll
    for (int o = 1; o < 64; o <<= 1) s += __shfl_xor(s, o);
    float mu = s * (1.0f / E);
    float qs = 0.f;
    #pragma unroll
    for (int i = 0; i < 8; i++) { float d = vv[i] - mu; qs += d * d; }
    #pragma unroll
    for (int o = 1; o < 64; o <<= 1) qs += __shfl_xor(qs, o);
    float rs = rsqrtf(qs * (1.0f / E) + EPS);
    float4 w0 = *(const float4*)(w + lane * 8), w1 = *(const float4*)(w + lane * 8 + 4);
    float4 b0 = *(const float4*)(bb + lane * 8), b1 = *(const float4*)(bb + lane * 8 + 4);
    float* op = out + (size_t)row * E + lane * 8;
    float4 o0, o1;
    o0.x = (vv[0] - mu) * rs * w0.x + b0.x;
    o0.y = (vv[1] - mu) * rs * w0.y + b0.y;
    o0.z = (vv[2] - mu) * rs * w0.z + b0.z;
    o0.w = (vv[3] - mu) * rs * w0.w + b0.w;
    o1.x = (vv[4] - mu) * rs * w1.x + b1.x;
    o1.y = (vv[5] - mu) * rs * w1.y + b1.y;
    o1.z = (vv[6] - mu) * rs * w1.z + b1.z;
    o1.w = (vv[7] - mu) * rs * w1.w + b1.w;
    *(float4*)op = o0;
    *(float4*)(op + 4) = o1;
}

// ---------------------------------------------------------------------------
// Weight conversion f32 -> bf16 into one packed buffer:
// [0,3EE): Wqkv   [3EE,4EE): Wo   [4EE,5EE): Wf
// ---------------------------------------------------------------------------
__global__ __launch_bounds__(256) void w2bf_kernel(
    const float* __restrict__ wqkv, const float* __restrict__ wo,
    const float* __restrict__ wf, unsigned short* __restrict__ out) {
    int base = (blockIdx.x * 256 + threadIdx.x) * 4;
    float4 v;
    if (base < 3 * E * E)           v = *(const float4*)(wqkv + base);
    else if (base < 4 * E * E)      v = *(const float4*)(wo + (base - 3 * E * E));
    else                            v = *(const float4*)(wf + (base - 4 * E * E));
    ushort4 o;
    o.x = f2bf(v.x); o.y = f2bf(v.y); o.z = f2bf(v.z); o.w = f2bf(v.w);
    *(ushort4*)(out + base) = o;
}

// ---------------------------------------------------------------------------
// bf16 MFMA GEMM (m97 structure): C[M,Ntot] = A[M,512] @ W[Ntot,512]^T + bias
// 128x128 tile, BK=32, 4 waves (2x2), each wave 64x64 = 4x4 MFMA 16x16x32.
//   OUT_MODE 0: bf16 [M,Ntot] -> C0
//   OUT_MODE 1: f32  = acc + bias + residf          -> C0   (out_proj + Zab)
//   OUT_MODE 2: f32  = acc + bias + bf16(residb)    -> C0   (ff + LN(x))
//   OUT_MODE 3: kv-split: col<512 -> bf16 K [M,512] in C0;
//               col>=512 -> bf16 V^T [B][512][1024] in C1
// ---------------------------------------------------------------------------
template <int OUT_MODE>
__global__ __launch_bounds__(256) void gemm_mfma(
    const unsigned short* __restrict__ A, const unsigned short* __restrict__ W,
    const float* __restrict__ bias,
    const float* __restrict__ residf, const unsigned short* __restrict__ residb,
    void* __restrict__ C0, void* __restrict__ C1, int Ntot) {
    __shared__ unsigned short As[128 * 32];
    __shared__ unsigned short Bs[128 * 32];
    const int t = threadIdx.x;
    const int wave = t >> 6, lane = t & 63;
    const int quad = lane >> 4, l16 = lane & 15;
    const int m0 = blockIdx.x * 128, n0 = blockIdx.y * 128;
    const int wm = (wave >> 1) * 64, wn = (wave & 1) * 64;

    const int srow = t >> 2;            // staging row (0..63)
    const int skof = (t & 3) * 8;       // staging k-offset (elements)

    f32x4 acc[4][4];
    #pragma unroll
    for (int i = 0; i < 4; i++)
        #pragma unroll
        for (int j = 0; j < 4; j++) acc[i][j] = (f32x4){0.f, 0.f, 0.f, 0.f};

    for (int k0 = 0; k0 < E; k0 += 32) {
        gload16(A + (size_t)(m0 + srow) * E + k0 + skof,        As + t * 8);
        gload16(A + (size_t)(m0 + 64 + srow) * E + k0 + skof,   As + 2048 + t * 8);
        gload16(W + (size_t)(n0 + srow) * E + k0 + skof,        Bs + t * 8);
        gload16(W + (size_t)(n0 + 64 + srow) * E + k0 + skof,   Bs + 2048 + t * 8);
        __syncthreads();
        short8 af[4], bfr[4];
        #pragma unroll
        for (int i = 0; i < 4; i++)
            af[i] = *(const short8*)&As[(wm + i * 16 + l16) * 32 + quad * 8];
        #pragma unroll
        for (int j = 0; j < 4; j++)
            bfr[j] = *(const short8*)&Bs[(wn + j * 16 + l16) * 32 + quad * 8];
        #pragma unroll
        for (int i = 0; i < 4; i++)
            #pragma unroll
            for (int j = 0; j < 4; j++)
                acc[i][j] = __builtin_amdgcn_mfma_f32_16x16x32_bf16(af[i], bfr[j], acc[i][j], 0, 0, 0);
        __syncthreads();
    }

    #pragma unroll
    for (int i = 0; i < 4; i++) {
        const int mrow0 = m0 + wm + i * 16 + quad * 4;
        #pragma unroll
        for (int j = 0; j < 4; j++) {
            const int ncol = n0 + wn + j * 16 + l16;
            const float bval = bias[ncol];
            if (OUT_MODE == 0) {
                #pragma unroll
                for (int r = 0; r < 4; r++)
                    ((unsigned short*)C0)[(size_t)(mrow0 + r) * Ntot + ncol] =
                        f2bf(acc[i][j][r] + bval);
            } else if (OUT_MODE == 1) {
                #pragma unroll
                for (int r = 0; r < 4; r++) {
                    size_t idx = (size_t)(mrow0 + r) * Ntot + ncol;
                    ((float*)C0)[idx] = acc[i][j][r] + bval + residf[idx];
                }
            } else if (OUT_MODE == 2) {
                #pragma unroll
                for (int r = 0; r < 4; r++) {
                    size_t idx = (size_t)(mrow0 + r) * Ntot + ncol;
                    ((float*)C0)[idx] = acc[i][j][r] + bval + bf2f(residb[idx]);
                }
            } else {
                if (ncol < 512) {
                    #pragma unroll
                    for (int r = 0; r < 4; r++)
                        ((unsigned short*)C0)[(size_t)(mrow0 + r) * 512 + ncol] =
                            f2bf(acc[i][j][r] + bval);
                } else {
                    const int nv = ncol - 512;
                    const int b2 = mrow0 >> 10, s0v = mrow0 & 1023;
                    ushort4 o;
                    o.x = f2bf(acc[i][j][0] + bval);
                    o.y = f2bf(acc[i][j][1] + bval);
                    o.z = f2bf(acc[i][j][2] + bval);
                    o.w = f2bf(acc[i][j][3] + bval);
                    *(ushort4*)((unsigned short*)C1 + ((size_t)b2 * 512 + nv) * 1024 + s0v) = o;
                }
            }
        }
    }
}

// ---------------------------------------------------------------------------
// MFMA attention, one head per block. Grid = B*H*(S/16) = 4096 blocks.
//   bx = b*512 + h*64 + qt. 3 barriers/block (vs 24 in the head-loop version).
//   aw accumulated via unsafeAtomicAdd of p/H (out_aw pre-zeroed by memset;
//   each address touched by exactly 8 blocks -> negligible contention).
// ---------------------------------------------------------------------------
__global__ __launch_bounds__(256, 1) void attn_mfma_kernel(
    const unsigned short* __restrict__ q,   // [B][S][E] bf16
    const unsigned short* __restrict__ k,   // [B][S][E] bf16
    const unsigned short* __restrict__ vt,  // [B][E][S] bf16
    unsigned short* __restrict__ ctx,       // [B][S][E] bf16
    float* __restrict__ aw) {               // [B][S][S] f32 (pre-zeroed)
    __shared__ unsigned short s_p[16][1032];
    __shared__ float s_red[2][4][16];

    const int t = threadIdx.x;
    const int wave = t >> 6, lane = t & 63;
    const int quad = lane >> 4, l16 = lane & 15;
    const int bx = blockIdx.x;
    const int b  = bx >> 9;
    const int h  = (bx >> 6) & 7;
    const int q0 = (bx & 63) * 16;

    const size_t qrow = ((size_t)(b * S + q0 + l16)) * E;

    // ---- scores: wave owns k-cols [wave*256, wave*256+256) ----
    short8 aq0 = *(const short8*)(q + qrow + h * 64 + quad * 8);
    short8 aq1 = *(const short8*)(q + qrow + h * 64 + 32 + quad * 8);
    f32x4 sacc[16];
    #pragma unroll
    for (int nt = 0; nt < 16; nt++) {
        const int kcol = wave * 256 + nt * 16 + l16;
        const unsigned short* kp = k + ((size_t)(b * S + kcol)) * E + h * 64 + quad * 8;
        short8 bk0 = *(const short8*)(kp);
        short8 bk1 = *(const short8*)(kp + 32);
        f32x4 c = (f32x4){0.f, 0.f, 0.f, 0.f};
        c = __builtin_amdgcn_mfma_f32_16x16x32_bf16(aq0, bk0, c, 0, 0, 0);
        c = __builtin_amdgcn_mfma_f32_16x16x32_bf16(aq1, bk1, c, 0, 0, 0);
        sacc[nt] = c * 0.125f;
    }

    // ---- softmax over 1024 cols (cross-wave via LDS) ----
    float gm[4], gs[4];
    #pragma unroll
    for (int r = 0; r < 4; r++) {
        float mv = sacc[0][r];
        #pragma unroll
        for (int nt = 1; nt < 16; nt++) mv = fmaxf(mv, sacc[nt][r]);
        #pragma unroll
        for (int o = 1; o < 16; o <<= 1) mv = fmaxf(mv, __shfl_xor(mv, o));
        gm[r] = mv;
    }
    if (l16 == 0) {
        #pragma unroll
        for (int r = 0; r < 4; r++) s_red[0][wave][quad * 4 + r] = gm[r];
    }
    __syncthreads();                                   // (A)
    #pragma unroll
    for (int r = 0; r < 4; r++) {
        int row = quad * 4 + r;
        gm[r] = fmaxf(fmaxf(s_red[0][0][row], s_red[0][1][row]),
                      fmaxf(s_red[0][2][row], s_red[0][3][row]));
    }
    float ls[4] = {0.f, 0.f, 0.f, 0.f};
    #pragma unroll
    for (int nt = 0; nt < 16; nt++)
        #pragma unroll
        for (int r = 0; r < 4; r++) {
            float p = __expf(sacc[nt][r] - gm[r]);
            sacc[nt][r] = p;
            ls[r] += p;
        }
    #pragma unroll
    for (int r = 0; r < 4; r++) {
        #pragma unroll
        for (int o = 1; o < 16; o <<= 1) ls[r] += __shfl_xor(ls[r], o);
    }
    if (l16 == 0) {
        #pragma unroll
        for (int r = 0; r < 4; r++) s_red[1][wave][quad * 4 + r] = ls[r];
    }
    __syncthreads();                                   // (B)
    #pragma unroll
    for (int r = 0; r < 4; r++) {
        int row = quad * 4 + r;
        gs[r] = 1.0f / (s_red[1][0][row] + s_red[1][1][row] +
                        s_red[1][2][row] + s_red[1][3][row]);
    }

    // ---- normalize, write P (bf16) to LDS ----
    #pragma unroll
    for (int nt = 0; nt < 16; nt++) {
        #pragma unroll
        for (int r = 0; r < 4; r++) {
            float p = sacc[nt][r] * gs[r];
            sacc[nt][r] = p;
            s_p[quad * 4 + r][wave * 256 + nt * 16 + l16] = f2bf(p);
        }
    }
    __syncthreads();                                   // (C)

    // ---- aw atomics (fire-and-forget; overlaps with PV) ----
    #pragma unroll
    for (int nt = 0; nt < 16; nt++) {
        #pragma unroll
        for (int r = 0; r < 4; r++)
            unsafeAtomicAdd(
                &aw[((size_t)(b * S + q0 + quad * 4 + r)) * S + wave * 256 + nt * 16 + l16],
                sacc[nt][r] * (1.0f / H));
    }

    // ---- PV: wave owns d-tile wave*16, contract full k=1024 ----
    f32x4 cacc = (f32x4){0.f, 0.f, 0.f, 0.f};
    const unsigned short* vrow =
        vt + ((size_t)(b * E + h * 64 + wave * 16 + l16)) * S;
    #pragma unroll 8
    for (int ks = 0; ks < 32; ks++) {
        short8 ap = *(const short8*)(&s_p[l16][ks * 32 + quad * 8]);
        short8 bv = *(const short8*)(vrow + ks * 32 + quad * 8);
        cacc = __builtin_amdgcn_mfma_f32_16x16x32_bf16(ap, bv, cacc, 0, 0, 0);
    }
    unsigned short* crow = ctx + ((size_t)(b * S + q0)) * E + h * 64 + wave * 16 + l16;
    #pragma unroll
    for (int r = 0; r < 4; r++)
        crow[(size_t)(quad * 4 + r) * E] = f2bf(cacc[r]);
}

// ---------------------------------------------------------------------------
extern "C" void kernel_launch(void* const* d_in, const int* in_sizes, int n_in,
                              void* d_out, int out_size, void* d_ws, size_t ws_size,
                              hipStream_t stream) {
    const float* Zab  = (const float*)d_in[0];
    const float* Za   = (const float*)d_in[1];
    const float* lnw  = (const float*)d_in[2];
    const float* lnb  = (const float*)d_in[3];
    const float* Wqkv = (const float*)d_in[4];
    const float* bqkv = (const float*)d_in[5];
    const float* Wo   = (const float*)d_in[6];
    const float* bo   = (const float*)d_in[7];
    const float* Wf   = (const float*)d_in[8];
    const float* bf   = (const float*)d_in[9];

    float* out_final = (float*)d_out;
    float* out_aw    = out_final + (size_t)B * S * E;

    char* ws = (char*)d_ws;
    unsigned short* qb   = (unsigned short*)(ws);               // 8 MB  [0,8M)
    unsigned short* kb   = (unsigned short*)(ws + (8u << 20));  // 8 MB  [8,16M)
    unsigned short* vtb  = (unsigned short*)(ws + (16u << 20)); // 8 MB  [16,24M)
    unsigned short* ctxb = (unsigned short*)(ws + (24u << 20)); // 8 MB  [24,32M)
    unsigned short* aqb  = (unsigned short*)(ws + (32u << 20)); // 8 MB  [32,40M)  later xn_bf
    unsigned short* akvb = (unsigned short*)(ws + (40u << 20)); // 8 MB  [40,48M)
    unsigned short* wbf  = (unsigned short*)(ws + (48u << 20)); // 2.62 MB
    float* xb = (float*)(ws);                                   // 16 MB [0,16M)  (qb/kb dead)
    float* tb = (float*)(ws + (16u << 20));                     // 16 MB [16,32M) (vtb/ctxb dead)
    unsigned short* xnb = aqb;                                  // reuse

    dim3 blk(256);

    // 0. zero attn_weights (atomic accumulation target)
    hipMemsetAsync(out_aw, 0, (size_t)B * S * S * sizeof(float), stream);

    // 1. weights -> bf16 (packed: qkv | o | f)
    w2bf_kernel<<<(5 * E * E) / 1024, blk, 0, stream>>>(Wqkv, Wo, Wf, wbf);

    // 2. LN(Zab), LN(Za) -> bf16
    ln_bf16_kernel<<<M / 4, blk, 0, stream>>>(Zab, lnw, lnb, aqb);
    ln_bf16_kernel<<<M / 4, blk, 0, stream>>>(Za,  lnw, lnb, akvb);

    // 3. q = LN(Zab)@Wq^T + bq (bf16); kv = LN(Za)@[Wk;Wv]^T + b (K bf16, V^T bf16)
    gemm_mfma<0><<<dim3(M / 128, 4), blk, 0, stream>>>(aqb,  wbf,               bqkv,     nullptr, nullptr, qb, nullptr, 512);
    gemm_mfma<3><<<dim3(M / 128, 8), blk, 0, stream>>>(akvb, wbf + (size_t)E*E, bqkv + E, nullptr, nullptr, kb, vtb, 1024);

    // 4. attention: one head per block -> ctx (bf16) + atomic attn_weights
    attn_mfma_kernel<<<B * H * (S / 16), blk, 0, stream>>>(qb, kb, vtb, ctxb, out_aw);

    // 5. x = ctx@Wo^T + bo + Zab (f32)
    gemm_mfma<1><<<dim3(M / 128, 4), blk, 0, stream>>>(ctxb, wbf + (size_t)3*E*E, bo, Zab, nullptr, xb, nullptr, 512);

    // 6. xn = LN(x) -> bf16
    ln_bf16_kernel<<<M / 4, blk, 0, stream>>>(xb, lnw, lnb, xnb);

    // 7. t = xn@Wf^T + bf + xn (f32)
    gemm_mfma<2><<<dim3(M / 128, 4), blk, 0, stream>>>(xnb, wbf + (size_t)4*E*E, bf, nullptr, xnb, tb, nullptr, 512);

    // 8. final = LN(t)
    ln_full_kernel<<<M / 4, blk, 0, stream>>>(tb, lnw, lnb, out_final);
}

// Round 5
// 309.984 us; speedup vs baseline: 1.3276x; 1.3276x over previous
//
#include <hip/hip_runtime.h>
#include <math.h>

#define EPS 1e-5f

constexpr int B = 8, S = 1024, E = 512, H = 8;
constexpr int M = B * S;          // 8192 rows

typedef __attribute__((ext_vector_type(8))) short short8;  // 8 bf16 (4 VGPRs)
typedef __attribute__((ext_vector_type(4))) float f32x4;

// fp32 -> bf16 bits, round-to-nearest-even
static __device__ __forceinline__ unsigned short f2bf(float f) {
    unsigned int x = __float_as_uint(f);
    x += 0x7FFFu + ((x >> 16) & 1u);
    return (unsigned short)(x >> 16);
}
static __device__ __forceinline__ float bf2f(unsigned short u) {
    return __uint_as_float(((unsigned int)u) << 16);
}

// async global->LDS, 16B per lane (global_load_lds_dwordx4)
typedef __attribute__((address_space(3))) unsigned int  lds_uint;
typedef __attribute__((address_space(1))) unsigned int  glb_uint;
static __device__ __forceinline__ void gload16(const unsigned short* g, unsigned short* l) {
    __builtin_amdgcn_global_load_lds((const glb_uint*)g, (lds_uint*)l, 16, 0, 0);
}

// ---------------------------------------------------------------------------
// LN -> bf16: one wave per row (E=512, 8 elems/lane), stats via 64-lane shuffles.
// ---------------------------------------------------------------------------
__global__ __launch_bounds__(256) void ln_bf16_kernel(
    const float* __restrict__ x, const float* __restrict__ w,
    const float* __restrict__ bb, unsigned short* __restrict__ out) {
    int row = blockIdx.x * 4 + (threadIdx.x >> 6);
    int lane = threadIdx.x & 63;
    const float* xr = x + (size_t)row * E + lane * 8;
    float4 v0 = *(const float4*)xr;
    float4 v1 = *(const float4*)(xr + 4);
    float vv[8] = {v0.x, v0.y, v0.z, v0.w, v1.x, v1.y, v1.z, v1.w};
    float s = 0.f;
    #pragma unroll
    for (int i = 0; i < 8; i++) s += vv[i];
    #pragma unroll
    for (int o = 1; o < 64; o <<= 1) s += __shfl_xor(s, o);
    float mu = s * (1.0f / E);
    float qs = 0.f;
    #pragma unroll
    for (int i = 0; i < 8; i++) { float d = vv[i] - mu; qs += d * d; }
    #pragma unroll
    for (int o = 1; o < 64; o <<= 1) qs += __shfl_xor(qs, o);
    float rs = rsqrtf(qs * (1.0f / E) + EPS);
    float4 w0 = *(const float4*)(w + lane * 8), w1 = *(const float4*)(w + lane * 8 + 4);
    float4 b0 = *(const float4*)(bb + lane * 8), b1 = *(const float4*)(bb + lane * 8 + 4);
    float ww[8] = {w0.x, w0.y, w0.z, w0.w, w1.x, w1.y, w1.z, w1.w};
    float bv[8] = {b0.x, b0.y, b0.z, b0.w, b1.x, b1.y, b1.z, b1.w};
    short8 o8;
    #pragma unroll
    for (int i = 0; i < 8; i++) o8[i] = (short)f2bf((vv[i] - mu) * rs * ww[i] + bv[i]);
    *(short8*)(out + (size_t)row * E + lane * 8) = o8;
}

// ---------------------------------------------------------------------------
// Full LN (fp32 out) for the final output — wave-per-row.
// ---------------------------------------------------------------------------
__global__ __launch_bounds__(256) void ln_full_kernel(
    const float* __restrict__ x, const float* __restrict__ w,
    const float* __restrict__ bb, float* __restrict__ out) {
    int row = blockIdx.x * 4 + (threadIdx.x >> 6);
    int lane = threadIdx.x & 63;
    const float* xr = x + (size_t)row * E + lane * 8;
    float4 v0 = *(const float4*)xr;
    float4 v1 = *(const float4*)(xr + 4);
    float vv[8] = {v0.x, v0.y, v0.z, v0.w, v1.x, v1.y, v1.z, v1.w};
    float s = 0.f;
    #pragma unroll
    for (int i = 0; i < 8; i++) s += vv[i];
    #pragma unroll
    for (int o = 1; o < 64; o <<= 1) s += __shfl_xor(s, o);
    float mu = s * (1.0f / E);
    float qs = 0.f;
    #pragma unroll
    for (int i = 0; i < 8; i++) { float d = vv[i] - mu; qs += d * d; }
    #pragma unroll
    for (int o = 1; o < 64; o <<= 1) qs += __shfl_xor(qs, o);
    float rs = rsqrtf(qs * (1.0f / E) + EPS);
    float4 w0 = *(const float4*)(w + lane * 8), w1 = *(const float4*)(w + lane * 8 + 4);
    float4 b0 = *(const float4*)(bb + lane * 8), b1 = *(const float4*)(bb + lane * 8 + 4);
    float* op = out + (size_t)row * E + lane * 8;
    float4 o0, o1;
    o0.x = (vv[0] - mu) * rs * w0.x + b0.x;
    o0.y = (vv[1] - mu) * rs * w0.y + b0.y;
    o0.z = (vv[2] - mu) * rs * w0.z + b0.z;
    o0.w = (vv[3] - mu) * rs * w0.w + b0.w;
    o1.x = (vv[4] - mu) * rs * w1.x + b1.x;
    o1.y = (vv[5] - mu) * rs * w1.y + b1.y;
    o1.z = (vv[6] - mu) * rs * w1.z + b1.z;
    o1.w = (vv[7] - mu) * rs * w1.w + b1.w;
    *(float4*)op = o0;
    *(float4*)(op + 4) = o1;
}

// ---------------------------------------------------------------------------
// Weight conversion f32 -> bf16 into one packed buffer:
// [0,3EE): Wqkv   [3EE,4EE): Wo   [4EE,5EE): Wf
// ---------------------------------------------------------------------------
__global__ __launch_bounds__(256) void w2bf_kernel(
    const float* __restrict__ wqkv, const float* __restrict__ wo,
    const float* __restrict__ wf, unsigned short* __restrict__ out) {
    int base = (blockIdx.x * 256 + threadIdx.x) * 4;
    float4 v;
    if (base < 3 * E * E)           v = *(const float4*)(wqkv + base);
    else if (base < 4 * E * E)      v = *(const float4*)(wo + (base - 3 * E * E));
    else                            v = *(const float4*)(wf + (base - 4 * E * E));
    ushort4 o;
    o.x = f2bf(v.x); o.y = f2bf(v.y); o.z = f2bf(v.z); o.w = f2bf(v.w);
    *(ushort4*)(out + base) = o;
}

// ---------------------------------------------------------------------------
// bf16 MFMA GEMM (m97 structure): C[M,Ntot] = A[M,512] @ W[Ntot,512]^T + bias
//   OUT_MODE 0: bf16 [M,Ntot] -> C0
//   OUT_MODE 1: f32  = acc + bias + residf          -> C0   (out_proj + Zab)
//   OUT_MODE 2: f32  = acc + bias + bf16(residb)    -> C0   (ff + LN(x))
//   OUT_MODE 3: kv-split: col<512 -> bf16 K [M,512] in C0;
//               col>=512 -> bf16 V^T [B][512][1024] in C1
// ---------------------------------------------------------------------------
template <int OUT_MODE>
__global__ __launch_bounds__(256) void gemm_mfma(
    const unsigned short* __restrict__ A, const unsigned short* __restrict__ W,
    const float* __restrict__ bias,
    const float* __restrict__ residf, const unsigned short* __restrict__ residb,
    void* __restrict__ C0, void* __restrict__ C1, int Ntot) {
    __shared__ unsigned short As[128 * 32];
    __shared__ unsigned short Bs[128 * 32];
    const int t = threadIdx.x;
    const int wave = t >> 6, lane = t & 63;
    const int quad = lane >> 4, l16 = lane & 15;
    const int m0 = blockIdx.x * 128, n0 = blockIdx.y * 128;
    const int wm = (wave >> 1) * 64, wn = (wave & 1) * 64;

    const int srow = t >> 2;            // staging row (0..63)
    const int skof = (t & 3) * 8;       // staging k-offset (elements)

    f32x4 acc[4][4];
    #pragma unroll
    for (int i = 0; i < 4; i++)
        #pragma unroll
        for (int j = 0; j < 4; j++) acc[i][j] = (f32x4){0.f, 0.f, 0.f, 0.f};

    for (int k0 = 0; k0 < E; k0 += 32) {
        gload16(A + (size_t)(m0 + srow) * E + k0 + skof,        As + t * 8);
        gload16(A + (size_t)(m0 + 64 + srow) * E + k0 + skof,   As + 2048 + t * 8);
        gload16(W + (size_t)(n0 + srow) * E + k0 + skof,        Bs + t * 8);
        gload16(W + (size_t)(n0 + 64 + srow) * E + k0 + skof,   Bs + 2048 + t * 8);
        __syncthreads();
        short8 af[4], bfr[4];
        #pragma unroll
        for (int i = 0; i < 4; i++)
            af[i] = *(const short8*)&As[(wm + i * 16 + l16) * 32 + quad * 8];
        #pragma unroll
        for (int j = 0; j < 4; j++)
            bfr[j] = *(const short8*)&Bs[(wn + j * 16 + l16) * 32 + quad * 8];
        #pragma unroll
        for (int i = 0; i < 4; i++)
            #pragma unroll
            for (int j = 0; j < 4; j++)
                acc[i][j] = __builtin_amdgcn_mfma_f32_16x16x32_bf16(af[i], bfr[j], acc[i][j], 0, 0, 0);
        __syncthreads();
    }

    #pragma unroll
    for (int i = 0; i < 4; i++) {
        const int mrow0 = m0 + wm + i * 16 + quad * 4;
        #pragma unroll
        for (int j = 0; j < 4; j++) {
            const int ncol = n0 + wn + j * 16 + l16;
            const float bval = bias[ncol];
            if (OUT_MODE == 0) {
                #pragma unroll
                for (int r = 0; r < 4; r++)
                    ((unsigned short*)C0)[(size_t)(mrow0 + r) * Ntot + ncol] =
                        f2bf(acc[i][j][r] + bval);
            } else if (OUT_MODE == 1) {
                #pragma unroll
                for (int r = 0; r < 4; r++) {
                    size_t idx = (size_t)(mrow0 + r) * Ntot + ncol;
                    ((float*)C0)[idx] = acc[i][j][r] + bval + residf[idx];
                }
            } else if (OUT_MODE == 2) {
                #pragma unroll
                for (int r = 0; r < 4; r++) {
                    size_t idx = (size_t)(mrow0 + r) * Ntot + ncol;
                    ((float*)C0)[idx] = acc[i][j][r] + bval + bf2f(residb[idx]);
                }
            } else {
                if (ncol < 512) {
                    #pragma unroll
                    for (int r = 0; r < 4; r++)
                        ((unsigned short*)C0)[(size_t)(mrow0 + r) * 512 + ncol] =
                            f2bf(acc[i][j][r] + bval);
                } else {
                    const int nv = ncol - 512;
                    const int b2 = mrow0 >> 10, s0v = mrow0 & 1023;
                    ushort4 o;
                    o.x = f2bf(acc[i][j][0] + bval);
                    o.y = f2bf(acc[i][j][1] + bval);
                    o.z = f2bf(acc[i][j][2] + bval);
                    o.w = f2bf(acc[i][j][3] + bval);
                    *(ushort4*)((unsigned short*)C1 + ((size_t)b2 * 512 + nv) * 1024 + s0v) = o;
                }
            }
        }
    }
}

// ---------------------------------------------------------------------------
// MFMA attention, head loop in-block (register aw accumulation — atomics were
// TCC-RMW-throughput-bound in round 4). Round-5 change: deep MLP via explicit
// batched register loads — 16 K-fragment loads per batch before the MFMA
// group, PV in 4 quarters of 8 V-loads + 8 P-ds_reads, 2 independent PV
// accumulators. __launch_bounds__(256,2) caps VGPR at 256 (2 waves/SIMD).
// ---------------------------------------------------------------------------
__global__ __launch_bounds__(256, 2) void attn_mfma_kernel(
    const unsigned short* __restrict__ q,   // [B][S][E] bf16
    const unsigned short* __restrict__ k,   // [B][S][E] bf16
    const unsigned short* __restrict__ vt,  // [B][E][S] bf16
    unsigned short* __restrict__ ctx,       // [B][S][E] bf16
    float* __restrict__ aw) {               // [B][S][S] f32
    __shared__ unsigned short s_p[16][1032];
    __shared__ float s_red[2][4][16];

    const int t = threadIdx.x;
    const int wave = t >> 6, lane = t & 63;
    const int quad = lane >> 4, l16 = lane & 15;
    const int b = blockIdx.x >> 6;
    const int q0 = (blockIdx.x & 63) * 16;

    const size_t qrow = ((size_t)(b * S + q0 + l16)) * E;

    f32x4 awacc[16];
    #pragma unroll
    for (int i = 0; i < 16; i++) awacc[i] = (f32x4){0.f, 0.f, 0.f, 0.f};

    for (int h = 0; h < H; h++) {
        short8 aq0 = *(const short8*)(q + qrow + h * 64 + quad * 8);
        short8 aq1 = *(const short8*)(q + qrow + h * 64 + 32 + quad * 8);

        // ---- scores: 2 batches of 16 deep loads, then 16 MFMA pairs ----
        f32x4 sacc[16];
        #pragma unroll
        for (int half = 0; half < 2; half++) {
            short8 kf0[8], kf1[8];
            #pragma unroll
            for (int i = 0; i < 8; i++) {
                const int kcol = wave * 256 + (half * 8 + i) * 16 + l16;
                const unsigned short* kp =
                    k + ((size_t)(b * S + kcol)) * E + h * 64 + quad * 8;
                kf0[i] = *(const short8*)(kp);
                kf1[i] = *(const short8*)(kp + 32);
            }
            #pragma unroll
            for (int i = 0; i < 8; i++) {
                f32x4 c = (f32x4){0.f, 0.f, 0.f, 0.f};
                c = __builtin_amdgcn_mfma_f32_16x16x32_bf16(aq0, kf0[i], c, 0, 0, 0);
                c = __builtin_amdgcn_mfma_f32_16x16x32_bf16(aq1, kf1[i], c, 0, 0, 0);
                sacc[half * 8 + i] = c * 0.125f;
            }
        }

        // ---- softmax over 1024 cols (cross-wave via LDS) ----
        float gm[4], gs[4];
        #pragma unroll
        for (int r = 0; r < 4; r++) {
            float mv = sacc[0][r];
            #pragma unroll
            for (int nt = 1; nt < 16; nt++) mv = fmaxf(mv, sacc[nt][r]);
            #pragma unroll
            for (int o = 1; o < 16; o <<= 1) mv = fmaxf(mv, __shfl_xor(mv, o));
            gm[r] = mv;
        }
        if (l16 == 0) {
            #pragma unroll
            for (int r = 0; r < 4; r++) s_red[0][wave][quad * 4 + r] = gm[r];
        }
        __syncthreads();                                   // (A)
        #pragma unroll
        for (int r = 0; r < 4; r++) {
            int row = quad * 4 + r;
            gm[r] = fmaxf(fmaxf(s_red[0][0][row], s_red[0][1][row]),
                          fmaxf(s_red[0][2][row], s_red[0][3][row]));
        }
        float ls[4] = {0.f, 0.f, 0.f, 0.f};
        #pragma unroll
        for (int nt = 0; nt < 16; nt++)
            #pragma unroll
            for (int r = 0; r < 4; r++) {
                float p = __expf(sacc[nt][r] - gm[r]);
                sacc[nt][r] = p;
                ls[r] += p;
            }
        #pragma unroll
        for (int r = 0; r < 4; r++) {
            #pragma unroll
            for (int o = 1; o < 16; o <<= 1) ls[r] += __shfl_xor(ls[r], o);
        }
        if (l16 == 0) {
            #pragma unroll
            for (int r = 0; r < 4; r++) s_red[1][wave][quad * 4 + r] = ls[r];
        }
        __syncthreads();                                   // (B)
        #pragma unroll
        for (int r = 0; r < 4; r++) {
            int row = quad * 4 + r;
            gs[r] = 1.0f / (s_red[1][0][row] + s_red[1][1][row] +
                            s_red[1][2][row] + s_red[1][3][row]);
        }

        // ---- normalize, accumulate aw, write P (bf16) to LDS ----
        #pragma unroll
        for (int nt = 0; nt < 16; nt++) {
            #pragma unroll
            for (int r = 0; r < 4; r++) {
                float p = sacc[nt][r] * gs[r];
                awacc[nt][r] += p;
                s_p[quad * 4 + r][wave * 256 + nt * 16 + l16] = f2bf(p);
            }
        }
        __syncthreads();                                   // (C)

        // ---- PV: 4 quarters of (8 V-loads + 8 P-ds_reads), 2 accumulators ----
        f32x4 cacc0 = (f32x4){0.f, 0.f, 0.f, 0.f};
        f32x4 cacc1 = (f32x4){0.f, 0.f, 0.f, 0.f};
        const unsigned short* vrow =
            vt + ((size_t)(b * E + h * 64 + wave * 16 + l16)) * S;
        #pragma unroll
        for (int qtr = 0; qtr < 4; qtr++) {
            short8 vf[8], pf[8];
            #pragma unroll
            for (int i = 0; i < 8; i++) {
                const int ks = qtr * 8 + i;
                vf[i] = *(const short8*)(vrow + ks * 32 + quad * 8);
            }
            #pragma unroll
            for (int i = 0; i < 8; i++) {
                const int ks = qtr * 8 + i;
                pf[i] = *(const short8*)(&s_p[l16][ks * 32 + quad * 8]);
            }
            #pragma unroll
            for (int i = 0; i < 8; i += 2) {
                cacc0 = __builtin_amdgcn_mfma_f32_16x16x32_bf16(pf[i],     vf[i],     cacc0, 0, 0, 0);
                cacc1 = __builtin_amdgcn_mfma_f32_16x16x32_bf16(pf[i + 1], vf[i + 1], cacc1, 0, 0, 0);
            }
        }
        f32x4 cacc = cacc0 + cacc1;
        unsigned short* crow = ctx + ((size_t)(b * S + q0)) * E + h * 64 + wave * 16 + l16;
        #pragma unroll
        for (int r = 0; r < 4; r++)
            crow[(size_t)(quad * 4 + r) * E] = f2bf(cacc[r]);
        // next head's s_p writes are fenced by its own (A)+(B) barriers
    }

    // ---- attn_weights (mean over heads) ----
    #pragma unroll
    for (int nt = 0; nt < 16; nt++) {
        #pragma unroll
        for (int r = 0; r < 4; r++)
            aw[((size_t)(b * S + q0 + quad * 4 + r)) * S + wave * 256 + nt * 16 + l16] =
                awacc[nt][r] * (1.0f / H);
    }
}

// ---------------------------------------------------------------------------
extern "C" void kernel_launch(void* const* d_in, const int* in_sizes, int n_in,
                              void* d_out, int out_size, void* d_ws, size_t ws_size,
                              hipStream_t stream) {
    const float* Zab  = (const float*)d_in[0];
    const float* Za   = (const float*)d_in[1];
    const float* lnw  = (const float*)d_in[2];
    const float* lnb  = (const float*)d_in[3];
    const float* Wqkv = (const float*)d_in[4];
    const float* bqkv = (const float*)d_in[5];
    const float* Wo   = (const float*)d_in[6];
    const float* bo   = (const float*)d_in[7];
    const float* Wf   = (const float*)d_in[8];
    const float* bf   = (const float*)d_in[9];

    float* out_final = (float*)d_out;
    float* out_aw    = out_final + (size_t)B * S * E;

    char* ws = (char*)d_ws;
    unsigned short* qb   = (unsigned short*)(ws);               // 8 MB  [0,8M)
    unsigned short* kb   = (unsigned short*)(ws + (8u << 20));  // 8 MB  [8,16M)
    unsigned short* vtb  = (unsigned short*)(ws + (16u << 20)); // 8 MB  [16,24M)
    unsigned short* ctxb = (unsigned short*)(ws + (24u << 20)); // 8 MB  [24,32M)
    unsigned short* aqb  = (unsigned short*)(ws + (32u << 20)); // 8 MB  [32,40M)  later xn_bf
    unsigned short* akvb = (unsigned short*)(ws + (40u << 20)); // 8 MB  [40,48M)
    unsigned short* wbf  = (unsigned short*)(ws + (48u << 20)); // 2.62 MB
    float* xb = (float*)(ws);                                   // 16 MB [0,16M)  (qb/kb dead)
    float* tb = (float*)(ws + (16u << 20));                     // 16 MB [16,32M) (vtb/ctxb dead)
    unsigned short* xnb = aqb;                                  // reuse

    dim3 blk(256);

    // 1. weights -> bf16 (packed: qkv | o | f)
    w2bf_kernel<<<(5 * E * E) / 1024, blk, 0, stream>>>(Wqkv, Wo, Wf, wbf);

    // 2. LN(Zab), LN(Za) -> bf16
    ln_bf16_kernel<<<M / 4, blk, 0, stream>>>(Zab, lnw, lnb, aqb);
    ln_bf16_kernel<<<M / 4, blk, 0, stream>>>(Za,  lnw, lnb, akvb);

    // 3. q = LN(Zab)@Wq^T + bq (bf16); kv = LN(Za)@[Wk;Wv]^T + b (K bf16, V^T bf16)
    gemm_mfma<0><<<dim3(M / 128, 4), blk, 0, stream>>>(aqb,  wbf,               bqkv,     nullptr, nullptr, qb, nullptr, 512);
    gemm_mfma<3><<<dim3(M / 128, 8), blk, 0, stream>>>(akvb, wbf + (size_t)E*E, bqkv + E, nullptr, nullptr, kb, vtb, 1024);

    // 4. attention (head loop, register aw) -> ctx (bf16) + attn_weights
    attn_mfma_kernel<<<B * (S / 16), blk, 0, stream>>>(qb, kb, vtb, ctxb, out_aw);

    // 5. x = ctx@Wo^T + bo + Zab (f32)
    gemm_mfma<1><<<dim3(M / 128, 4), blk, 0, stream>>>(ctxb, wbf + (size_t)3*E*E, bo, Zab, nullptr, xb, nullptr, 512);

    // 6. xn = LN(x) -> bf16
    ln_bf16_kernel<<<M / 4, blk, 0, stream>>>(xb, lnw, lnb, xnb);

    // 7. t = xn@Wf^T + bf + xn (f32)
    gemm_mfma<2><<<dim3(M / 128, 4), blk, 0, stream>>>(xnb, wbf + (size_t)4*E*E, bf, nullptr, xnb, tb, nullptr, 512);

    // 8. final = LN(t)
    ln_full_kernel<<<M / 4, blk, 0, stream>>>(tb, lnw, lnb, out_final);
}